// Round 1
// baseline (514.561 us; speedup 1.0000x reference)
//
#include <hip/hip_runtime.h>
#include <math.h>

// RoPE+SDPA attention, fp32 baseline (round 0 — correctness + counters).
// B=8 L=1024 H=8 Dh=64 HID=512.
// ws layout (floats): cos[1024*32] | sin[1024*32] | Q[B*H*L*64] | K | V | AO[B*L*512]
// total = 65536 + 4*4194304 floats = 64.25 MiB.

#define BB 8
#define LL 1024
#define HH 8
#define DH 64
#define HID 512

// ---------------- RoPE table: cos/sin(l * 10000^{-j/32}) ----------------
__global__ void rope_table_kernel(float* __restrict__ cos_t, float* __restrict__ sin_t) {
    int idx = blockIdx.x * blockDim.x + threadIdx.x;   // [0, 1024*32)
    if (idx >= LL * 32) return;
    int l = idx >> 5, j = idx & 31;
    // inv_freq = 10000^{-j/32} = 2^{-j/32 * log2(10000)}
    float inv = exp2f(-(float)j * (13.287712379549449f / 32.0f));
    float th = (float)l * inv;
    cos_t[idx] = cosf(th);
    sin_t[idx] = sinf(th);
}

// ---------------- QKV projection GEMM (fp32, 128x128 tile, 8x8 microtile) ----
// C[m,n] = sum_k x[m,k] * W[n,k];  scatter epilogue into [B,H,L,DH]
__global__ __launch_bounds__(256) void qkv_gemm_kernel(
    const float* __restrict__ x, const float* __restrict__ Wq,
    const float* __restrict__ Wk, const float* __restrict__ Wv,
    float* __restrict__ Q, float* __restrict__ K, float* __restrict__ V)
{
    __shared__ float As[16][132];
    __shared__ float Bs[16][132];

    const int mt = blockIdx.x;          // 0..63
    const int nt = blockIdx.y;          // 0..11
    const int mbase = mt * 128;
    const int mat = nt >> 2;            // 0=Q,1=K,2=V
    const float* W = (mat == 0) ? Wq : ((mat == 1) ? Wk : Wv);
    float* Dst     = (mat == 0) ? Q  : ((mat == 1) ? K  : V);
    const int nW = (nt & 3) * 128;      // column base within this W (0..384)

    const int tid = threadIdx.x;
    const int lr = tid >> 1;            // 0..127
    const int lk = (tid & 1) * 8;       // 0 or 8
    const int ty = tid >> 4, tx = tid & 15;
    const int m0 = ty * 8, n0 = tx * 8;

    float acc[8][8];
    #pragma unroll
    for (int i = 0; i < 8; ++i)
        #pragma unroll
        for (int j = 0; j < 8; ++j) acc[i][j] = 0.f;

    for (int kc = 0; kc < 512; kc += 16) {
        const float4* ap = (const float4*)(x + (size_t)(mbase + lr) * 512 + kc + lk);
        float4 a0 = ap[0], a1 = ap[1];
        const float4* bp = (const float4*)(W + (size_t)(nW + lr) * 512 + kc + lk);
        float4 b0 = bp[0], b1 = bp[1];
        __syncthreads();   // previous compute done reading LDS
        As[lk + 0][lr] = a0.x; As[lk + 1][lr] = a0.y; As[lk + 2][lr] = a0.z; As[lk + 3][lr] = a0.w;
        As[lk + 4][lr] = a1.x; As[lk + 5][lr] = a1.y; As[lk + 6][lr] = a1.z; As[lk + 7][lr] = a1.w;
        Bs[lk + 0][lr] = b0.x; Bs[lk + 1][lr] = b0.y; Bs[lk + 2][lr] = b0.z; Bs[lk + 3][lr] = b0.w;
        Bs[lk + 4][lr] = b1.x; Bs[lk + 5][lr] = b1.y; Bs[lk + 6][lr] = b1.z; Bs[lk + 7][lr] = b1.w;
        __syncthreads();
        #pragma unroll
        for (int k = 0; k < 16; ++k) {
            float a[8], bb[8];
            *(float4*)&a[0]  = *(const float4*)&As[k][m0];
            *(float4*)&a[4]  = *(const float4*)&As[k][m0 + 4];
            *(float4*)&bb[0] = *(const float4*)&Bs[k][n0];
            *(float4*)&bb[4] = *(const float4*)&Bs[k][n0 + 4];
            #pragma unroll
            for (int i = 0; i < 8; ++i)
                #pragma unroll
                for (int j = 0; j < 8; ++j)
                    acc[i][j] = fmaf(a[i], bb[j], acc[i][j]);
        }
    }

    // scatter into [B,H,L,DH]; n0 is a multiple of 8 -> 8 cols stay within one head
    const int ncol = nW + n0;           // 0..511 within this matrix
    const int h = ncol >> 6, d = ncol & 63;
    #pragma unroll
    for (int i = 0; i < 8; ++i) {
        int m = mbase + m0 + i;
        int b = m >> 10, l = m & 1023;
        float* dp = Dst + (((size_t)(b * HH + h) * LL + l) * 64 + d);
        *(float4*)dp       = make_float4(acc[i][0], acc[i][1], acc[i][2], acc[i][3]);
        *(float4*)(dp + 4) = make_float4(acc[i][4], acc[i][5], acc[i][6], acc[i][7]);
    }
}

// ---------------- RoPE apply (in-place on Q then K) ----------------
__global__ void rope_apply_kernel(float* __restrict__ q, float* __restrict__ k,
                                  const float* __restrict__ cos_t,
                                  const float* __restrict__ sin_t) {
    int idx = blockIdx.x * blockDim.x + threadIdx.x;   // [0, 2*B*H*L*32)
    const int total = BB * HH * LL * 32;
    float* T = q;
    if (idx >= total) { T = k; idx -= total; }
    int j = idx & 31;
    int bhl = idx >> 5;
    int l = bhl & (LL - 1);
    float c = cos_t[l * 32 + j], s = sin_t[l * 32 + j];
    size_t base = (size_t)bhl * 64;
    float x0 = T[base + j], x1 = T[base + j + 32];
    T[base + j]      = x0 * c - x1 * s;
    T[base + j + 32] = x1 * c + x0 * s;
}

// ---------------- Flash attention fp32 (64-row Q tile, online softmax) ------
__global__ __launch_bounds__(256) void attn_kernel(
    const float* __restrict__ Q, const float* __restrict__ K,
    const float* __restrict__ V, float* __restrict__ O /* [B,L,HID] */)
{
    __shared__ float Qst[64][68];   // [d][r]
    __shared__ float Kst[64][68];   // [d][c]
    __shared__ float Vs[64][68];    // [k][d]
    __shared__ float Pt[64][68];    // [k][r]

    const int qt = blockIdx.x;      // 0..15
    const int bh = blockIdx.y;      // 0..63
    const int b = bh >> 3, h = bh & 7;
    const float* Qp = Q + (size_t)bh * LL * 64;
    const float* Kp = K + (size_t)bh * LL * 64;
    const float* Vp = V + (size_t)bh * LL * 64;

    const int tid = threadIdx.x;
    const int ty = tid >> 4, tx = tid & 15;
    const int r0 = ty * 4, c0 = tx * 4;

    // load Q tile transposed: Qst[d][r]
    {
        int row = tid >> 2;
        int d0 = (tid & 3) * 16;
        const float4* qp4 = (const float4*)(Qp + (size_t)(qt * 64 + row) * 64 + d0);
        #pragma unroll
        for (int f = 0; f < 4; ++f) {
            float4 v = qp4[f];
            Qst[d0 + f * 4 + 0][row] = v.x;
            Qst[d0 + f * 4 + 1][row] = v.y;
            Qst[d0 + f * 4 + 2][row] = v.z;
            Qst[d0 + f * 4 + 3][row] = v.w;
        }
    }

    float m_i[4], l_i[4], acc[4][4];
    #pragma unroll
    for (int i = 0; i < 4; ++i) {
        m_i[i] = -1e30f; l_i[i] = 0.f;
        #pragma unroll
        for (int j = 0; j < 4; ++j) acc[i][j] = 0.f;
    }

    for (int kt = 0; kt < 16; ++kt) {
        __syncthreads();   // previous PV done (and Q load on first iter)
        {
            int row = tid >> 2;
            int d0 = (tid & 3) * 16;
            const float4* kp4 = (const float4*)(Kp + (size_t)(kt * 64 + row) * 64 + d0);
            const float4* vp4 = (const float4*)(Vp + (size_t)(kt * 64 + row) * 64 + d0);
            #pragma unroll
            for (int f = 0; f < 4; ++f) {
                float4 kv = kp4[f];
                Kst[d0 + f * 4 + 0][row] = kv.x;
                Kst[d0 + f * 4 + 1][row] = kv.y;
                Kst[d0 + f * 4 + 2][row] = kv.z;
                Kst[d0 + f * 4 + 3][row] = kv.w;
                float4 vv = vp4[f];
                *(float4*)&Vs[row][d0 + f * 4] = vv;
            }
        }
        __syncthreads();

        // S = (Q K^T) * 0.125  (4x4 per thread)
        float s[4][4];
        #pragma unroll
        for (int i = 0; i < 4; ++i)
            #pragma unroll
            for (int j = 0; j < 4; ++j) s[i][j] = 0.f;
        #pragma unroll 16
        for (int d = 0; d < 64; ++d) {
            float a[4], bb[4];
            *(float4*)a  = *(const float4*)&Qst[d][r0];
            *(float4*)bb = *(const float4*)&Kst[d][c0];
            #pragma unroll
            for (int i = 0; i < 4; ++i)
                #pragma unroll
                for (int j = 0; j < 4; ++j)
                    s[i][j] = fmaf(a[i], bb[j], s[i][j]);
        }

        // online softmax per row (rows r0..r0+3; cols spread over 16 lanes)
        #pragma unroll
        for (int i = 0; i < 4; ++i) {
            #pragma unroll
            for (int j = 0; j < 4; ++j) s[i][j] *= 0.125f;
            float mx = fmaxf(fmaxf(s[i][0], s[i][1]), fmaxf(s[i][2], s[i][3]));
            mx = fmaxf(mx, __shfl_xor(mx, 1));
            mx = fmaxf(mx, __shfl_xor(mx, 2));
            mx = fmaxf(mx, __shfl_xor(mx, 4));
            mx = fmaxf(mx, __shfl_xor(mx, 8));
            float mnew = fmaxf(m_i[i], mx);
            float alpha = __expf(m_i[i] - mnew);
            float rsum = 0.f;
            #pragma unroll
            for (int j = 0; j < 4; ++j) {
                float p = __expf(s[i][j] - mnew);
                s[i][j] = p;
                rsum += p;
            }
            rsum += __shfl_xor(rsum, 1);
            rsum += __shfl_xor(rsum, 2);
            rsum += __shfl_xor(rsum, 4);
            rsum += __shfl_xor(rsum, 8);
            l_i[i] = l_i[i] * alpha + rsum;
            m_i[i] = mnew;
            #pragma unroll
            for (int j = 0; j < 4; ++j) acc[i][j] *= alpha;
        }

        // write P transposed: Pt[c][r]
        #pragma unroll
        for (int i = 0; i < 4; ++i)
            #pragma unroll
            for (int j = 0; j < 4; ++j)
                Pt[c0 + j][r0 + i] = s[i][j];
        __syncthreads();

        // O += P V   (thread owns rows r0.., dims c0..)
        #pragma unroll 16
        for (int k = 0; k < 64; ++k) {
            float p[4], vv[4];
            *(float4*)p  = *(const float4*)&Pt[k][r0];
            *(float4*)vv = *(const float4*)&Vs[k][c0];
            #pragma unroll
            for (int i = 0; i < 4; ++i)
                #pragma unroll
                for (int j = 0; j < 4; ++j)
                    acc[i][j] = fmaf(p[i], vv[j], acc[i][j]);
        }
    }

    // epilogue: O[b, l, h*64+d] = acc / l_i
    #pragma unroll
    for (int i = 0; i < 4; ++i) {
        float inv = 1.0f / l_i[i];
        int row = qt * 64 + r0 + i;
        float4 o = make_float4(acc[i][0] * inv, acc[i][1] * inv,
                               acc[i][2] * inv, acc[i][3] * inv);
        *(float4*)(O + ((size_t)(b * LL + row) * HID) + h * 64 + c0) = o;
    }
}

// ---------------- Output projection GEMM ----------------
__global__ __launch_bounds__(256) void out_gemm_kernel(
    const float* __restrict__ AO, const float* __restrict__ Wo,
    float* __restrict__ out)
{
    __shared__ float As[16][132];
    __shared__ float Bs[16][132];

    const int mt = blockIdx.x;          // 0..63
    const int nt = blockIdx.y;          // 0..3
    const int mbase = mt * 128;
    const int nbase = nt * 128;

    const int tid = threadIdx.x;
    const int lr = tid >> 1;
    const int lk = (tid & 1) * 8;
    const int ty = tid >> 4, tx = tid & 15;
    const int m0 = ty * 8, n0 = tx * 8;

    float acc[8][8];
    #pragma unroll
    for (int i = 0; i < 8; ++i)
        #pragma unroll
        for (int j = 0; j < 8; ++j) acc[i][j] = 0.f;

    for (int kc = 0; kc < 512; kc += 16) {
        const float4* ap = (const float4*)(AO + (size_t)(mbase + lr) * 512 + kc + lk);
        float4 a0 = ap[0], a1 = ap[1];
        const float4* bp = (const float4*)(Wo + (size_t)(nbase + lr) * 512 + kc + lk);
        float4 b0 = bp[0], b1 = bp[1];
        __syncthreads();
        As[lk + 0][lr] = a0.x; As[lk + 1][lr] = a0.y; As[lk + 2][lr] = a0.z; As[lk + 3][lr] = a0.w;
        As[lk + 4][lr] = a1.x; As[lk + 5][lr] = a1.y; As[lk + 6][lr] = a1.z; As[lk + 7][lr] = a1.w;
        Bs[lk + 0][lr] = b0.x; Bs[lk + 1][lr] = b0.y; Bs[lk + 2][lr] = b0.z; Bs[lk + 3][lr] = b0.w;
        Bs[lk + 4][lr] = b1.x; Bs[lk + 5][lr] = b1.y; Bs[lk + 6][lr] = b1.z; Bs[lk + 7][lr] = b1.w;
        __syncthreads();
        #pragma unroll
        for (int k = 0; k < 16; ++k) {
            float a[8], bb[8];
            *(float4*)&a[0]  = *(const float4*)&As[k][m0];
            *(float4*)&a[4]  = *(const float4*)&As[k][m0 + 4];
            *(float4*)&bb[0] = *(const float4*)&Bs[k][n0];
            *(float4*)&bb[4] = *(const float4*)&Bs[k][n0 + 4];
            #pragma unroll
            for (int i = 0; i < 8; ++i)
                #pragma unroll
                for (int j = 0; j < 8; ++j)
                    acc[i][j] = fmaf(a[i], bb[j], acc[i][j]);
        }
    }

    #pragma unroll
    for (int i = 0; i < 8; ++i) {
        int m = mbase + m0 + i;
        float* dp = out + (size_t)m * 512 + nbase + n0;
        *(float4*)dp       = make_float4(acc[i][0], acc[i][1], acc[i][2], acc[i][3]);
        *(float4*)(dp + 4) = make_float4(acc[i][4], acc[i][5], acc[i][6], acc[i][7]);
    }
}

extern "C" void kernel_launch(void* const* d_in, const int* in_sizes, int n_in,
                              void* d_out, int out_size, void* d_ws, size_t ws_size,
                              hipStream_t stream) {
    const float* x  = (const float*)d_in[0];
    const float* Wq = (const float*)d_in[1];
    const float* Wk = (const float*)d_in[2];
    const float* Wv = (const float*)d_in[3];
    const float* Wo = (const float*)d_in[4];
    float* out = (float*)d_out;

    float* ws = (float*)d_ws;
    const size_t tblN = (size_t)LL * 32;           // 32768
    const size_t qkvN = (size_t)BB * HH * LL * 64; // 4194304
    float* cos_t = ws;
    float* sin_t = cos_t + tblN;
    float* Q  = sin_t + tblN;
    float* K  = Q + qkvN;
    float* V  = K + qkvN;
    float* AO = V + qkvN;

    hipLaunchKernelGGL(rope_table_kernel, dim3((LL * 32 + 255) / 256), dim3(256), 0, stream,
                       cos_t, sin_t);
    hipLaunchKernelGGL(qkv_gemm_kernel, dim3(64, 12), dim3(256), 0, stream,
                       x, Wq, Wk, Wv, Q, K, V);
    hipLaunchKernelGGL(rope_apply_kernel, dim3((2 * BB * HH * LL * 32) / 256), dim3(256), 0, stream,
                       Q, K, cos_t, sin_t);
    hipLaunchKernelGGL(attn_kernel, dim3(16, 64), dim3(256), 0, stream,
                       Q, K, V, AO);
    hipLaunchKernelGGL(out_gemm_kernel, dim3(64, 4), dim3(256), 0, stream,
                       AO, Wo, out);
}

// Round 2
// 366.732 us; speedup vs baseline: 1.4031x; 1.4031x over previous
//
#include <hip/hip_runtime.h>
#include <math.h>

// RoPE+SDPA attention. Round 1: bf16-MFMA flash attention; fp32 GEMMs.
// B=8 L=1024 H=8 Dh=64 HID=512.
// ws (bytes): cos f32[32768] | sin f32[32768] | Qb bf16[4M] | Kb bf16[4M]
//             | Vt bf16[4M, layout B,H,D,L] | AO f32[B*L*512]

#define BB 8
#define LL 1024
#define HH 8
#define DH 64
#define HID 512

typedef __bf16 bf16x8 __attribute__((ext_vector_type(8)));
typedef float f32x4 __attribute__((ext_vector_type(4)));
typedef unsigned short u16x8 __attribute__((ext_vector_type(8)));

__device__ inline unsigned short f2bf(float f) {
    union { float f; unsigned u; } v; v.f = f;
    unsigned r = v.u + 0x7fffu + ((v.u >> 16) & 1u);
    return (unsigned short)(r >> 16);
}
__device__ inline float bf2f(unsigned short s) {
    union { unsigned u; float f; } v; v.u = ((unsigned)s) << 16;
    return v.f;
}

// ---------------- RoPE table ----------------
__global__ void rope_table_kernel(float* __restrict__ cos_t, float* __restrict__ sin_t) {
    int idx = blockIdx.x * blockDim.x + threadIdx.x;
    if (idx >= LL * 32) return;
    int l = idx >> 5, j = idx & 31;
    float inv = exp2f(-(float)j * (13.287712379549449f / 32.0f));
    float th = (float)l * inv;
    cos_t[idx] = cosf(th);
    sin_t[idx] = sinf(th);
}

// ---------------- QKV projection GEMM (fp32 compute, bf16 epilogue) ---------
__global__ __launch_bounds__(256) void qkv_gemm_kernel(
    const float* __restrict__ x, const float* __restrict__ Wq,
    const float* __restrict__ Wk, const float* __restrict__ Wv,
    unsigned short* __restrict__ Qb, unsigned short* __restrict__ Kb,
    unsigned short* __restrict__ Vt)
{
    __shared__ float As[16][132];
    __shared__ float Bs[16][132];

    const int mt = blockIdx.x;          // 0..63
    const int nt = blockIdx.y;          // 0..11
    const int mbase = mt * 128;
    const int mat = nt >> 2;            // 0=Q,1=K,2=V
    const float* W = (mat == 0) ? Wq : ((mat == 1) ? Wk : Wv);
    const int nW = (nt & 3) * 128;

    const int tid = threadIdx.x;
    const int lr = tid >> 1;
    const int lk = (tid & 1) * 8;
    const int ty = tid >> 4, tx = tid & 15;
    const int m0 = ty * 8, n0 = tx * 8;

    float acc[8][8];
    #pragma unroll
    for (int i = 0; i < 8; ++i)
        #pragma unroll
        for (int j = 0; j < 8; ++j) acc[i][j] = 0.f;

    for (int kc = 0; kc < 512; kc += 16) {
        const float4* ap = (const float4*)(x + (size_t)(mbase + lr) * 512 + kc + lk);
        float4 a0 = ap[0], a1 = ap[1];
        const float4* bp = (const float4*)(W + (size_t)(nW + lr) * 512 + kc + lk);
        float4 b0 = bp[0], b1 = bp[1];
        __syncthreads();
        As[lk + 0][lr] = a0.x; As[lk + 1][lr] = a0.y; As[lk + 2][lr] = a0.z; As[lk + 3][lr] = a0.w;
        As[lk + 4][lr] = a1.x; As[lk + 5][lr] = a1.y; As[lk + 6][lr] = a1.z; As[lk + 7][lr] = a1.w;
        Bs[lk + 0][lr] = b0.x; Bs[lk + 1][lr] = b0.y; Bs[lk + 2][lr] = b0.z; Bs[lk + 3][lr] = b0.w;
        Bs[lk + 4][lr] = b1.x; Bs[lk + 5][lr] = b1.y; Bs[lk + 6][lr] = b1.z; Bs[lk + 7][lr] = b1.w;
        __syncthreads();
        #pragma unroll
        for (int k = 0; k < 16; ++k) {
            float a[8], bb[8];
            *(float4*)&a[0]  = *(const float4*)&As[k][m0];
            *(float4*)&a[4]  = *(const float4*)&As[k][m0 + 4];
            *(float4*)&bb[0] = *(const float4*)&Bs[k][n0];
            *(float4*)&bb[4] = *(const float4*)&Bs[k][n0 + 4];
            #pragma unroll
            for (int i = 0; i < 8; ++i)
                #pragma unroll
                for (int j = 0; j < 8; ++j)
                    acc[i][j] = fmaf(a[i], bb[j], acc[i][j]);
        }
    }

    const int ncol = nW + n0;
    const int h = ncol >> 6, d = ncol & 63;
    if (mat < 2) {
        unsigned short* D = (mat == 0) ? Qb : Kb;
        #pragma unroll
        for (int i = 0; i < 8; ++i) {
            int m = mbase + m0 + i;
            int b = m >> 10, l = m & 1023;
            u16x8 pk;
            #pragma unroll
            for (int j = 0; j < 8; ++j) pk[j] = f2bf(acc[i][j]);
            *(u16x8*)(D + (((size_t)(b * HH + h) * LL + l) * 64 + d)) = pk;
        }
    } else {
        // V transposed: Vt[b][h][d][l]
        int m = mbase + m0;
        int b = m >> 10, l = m & 1023;
        #pragma unroll
        for (int j = 0; j < 8; ++j) {
            u16x8 pk;
            #pragma unroll
            for (int i = 0; i < 8; ++i) pk[i] = f2bf(acc[i][j]);
            *(u16x8*)(Vt + ((size_t)(b * HH + h) * 64 + d + j) * LL + l) = pk;
        }
    }
}

// ---------------- RoPE apply (bf16 in-place; Q gets *0.125 folded) ----------
__global__ void rope_apply_kernel(unsigned short* __restrict__ q,
                                  unsigned short* __restrict__ k,
                                  const float* __restrict__ cos_t,
                                  const float* __restrict__ sin_t) {
    int idx = blockIdx.x * blockDim.x + threadIdx.x;
    const int total = BB * HH * LL * 32;
    unsigned short* T = q;
    float sc = 0.125f;
    if (idx >= total) { T = k; idx -= total; sc = 1.0f; }
    int j = idx & 31;
    int bhl = idx >> 5;
    int l = bhl & (LL - 1);
    float c = cos_t[l * 32 + j], s = sin_t[l * 32 + j];
    size_t base = (size_t)bhl * 64;
    float x0 = bf2f(T[base + j]), x1 = bf2f(T[base + j + 32]);
    T[base + j]      = f2bf((x0 * c - x1 * s) * sc);
    T[base + j + 32] = f2bf((x1 * c + x0 * s) * sc);
}

// ---------------- Flash attention, bf16 MFMA --------------------------------
// Block: 256 threads = 4 waves; wave w owns q-rows [qt*64 + w*16, +16).
// Per 64-wide K tile: 8 QK^T mfma -> online softmax in-register ->
// P->bf16 via per-wave LDS -> 8 PV mfma (V^T frags from global).
__global__ __launch_bounds__(256) void attn_kernel(
    const unsigned short* __restrict__ Q, const unsigned short* __restrict__ K,
    const unsigned short* __restrict__ Vt, float* __restrict__ O)
{
    __shared__ unsigned short Plds[4][16][72];   // per-wave P tile [q=16][k=64], stride 72

    const int qt = blockIdx.x;      // 0..15
    const int bh = blockIdx.y;      // 0..63
    const int b = bh >> 3, h = bh & 7;
    const int tid = threadIdx.x;
    const int w = tid >> 6;
    const int lane = tid & 63;
    const int l15 = lane & 15;
    const int koff = (lane >> 4) * 8;

    const unsigned short* Qp = Q + (size_t)bh * LL * 64;
    const unsigned short* Kp = K + (size_t)bh * LL * 64;
    const unsigned short* Vp = Vt + (size_t)bh * 64 * LL;

    const int q0 = qt * 64 + w * 16;

    // Q A-fragments (row = l15, k = koff.. / +32), held for whole kernel
    bf16x8 qf0 = *(const bf16x8*)(Qp + (size_t)(q0 + l15) * 64 + koff);
    bf16x8 qf1 = *(const bf16x8*)(Qp + (size_t)(q0 + l15) * 64 + koff + 32);

    float m_i[4], l_i[4];
    f32x4 opv[4];
    #pragma unroll
    for (int r = 0; r < 4; ++r) { m_i[r] = -1e30f; l_i[r] = 0.f; }
    #pragma unroll
    for (int dt = 0; dt < 4; ++dt) opv[dt] = (f32x4){0.f, 0.f, 0.f, 0.f};

    for (int kt = 0; kt < 16; ++kt) {
        const int kbase = kt * 64;

        // S = Q K^T (already scaled: Q carries 0.125)
        f32x4 s[4];
        #pragma unroll
        for (int nt = 0; nt < 4; ++nt) {
            const unsigned short* kp = Kp + (size_t)(kbase + nt * 16 + l15) * 64 + koff;
            bf16x8 kf0 = *(const bf16x8*)kp;
            bf16x8 kf1 = *(const bf16x8*)(kp + 32);
            f32x4 z = {0.f, 0.f, 0.f, 0.f};
            z = __builtin_amdgcn_mfma_f32_16x16x32_bf16(qf0, kf0, z, 0, 0, 0);
            z = __builtin_amdgcn_mfma_f32_16x16x32_bf16(qf1, kf1, z, 0, 0, 0);
            s[nt] = z;
        }

        // online softmax: lane holds rows (lane>>4)*4+r, col nt*16+l15
        float alpha[4];
        #pragma unroll
        for (int r = 0; r < 4; ++r) {
            float mx = fmaxf(fmaxf(s[0][r], s[1][r]), fmaxf(s[2][r], s[3][r]));
            mx = fmaxf(mx, __shfl_xor(mx, 1));
            mx = fmaxf(mx, __shfl_xor(mx, 2));
            mx = fmaxf(mx, __shfl_xor(mx, 4));
            mx = fmaxf(mx, __shfl_xor(mx, 8));
            float mnew = fmaxf(m_i[r], mx);
            float a = __expf(m_i[r] - mnew);
            m_i[r] = mnew;
            alpha[r] = a;
            float rsum = 0.f;
            #pragma unroll
            for (int nt = 0; nt < 4; ++nt) {
                float p = __expf(s[nt][r] - mnew);
                s[nt][r] = p;
                rsum += p;
            }
            rsum += __shfl_xor(rsum, 1);
            rsum += __shfl_xor(rsum, 2);
            rsum += __shfl_xor(rsum, 4);
            rsum += __shfl_xor(rsum, 8);
            l_i[r] = l_i[r] * a + rsum;
        }
        #pragma unroll
        for (int dt = 0; dt < 4; ++dt)
            #pragma unroll
            for (int r = 0; r < 4; ++r) opv[dt][r] *= alpha[r];

        // P -> bf16 via per-wave LDS (no cross-wave sync needed)
        #pragma unroll
        for (int nt = 0; nt < 4; ++nt)
            #pragma unroll
            for (int r = 0; r < 4; ++r)
                Plds[w][(lane >> 4) * 4 + r][nt * 16 + l15] = f2bf(s[nt][r]);

        bf16x8 pf0 = *(const bf16x8*)&Plds[w][l15][koff];
        bf16x8 pf1 = *(const bf16x8*)&Plds[w][l15][koff + 32];

        // O += P V  (V^T fragments: row d, contiguous l)
        #pragma unroll
        for (int dt = 0; dt < 4; ++dt) {
            const unsigned short* vp = Vp + (size_t)(dt * 16 + l15) * LL + kbase + koff;
            bf16x8 vf0 = *(const bf16x8*)vp;
            bf16x8 vf1 = *(const bf16x8*)(vp + 32);
            opv[dt] = __builtin_amdgcn_mfma_f32_16x16x32_bf16(pf0, vf0, opv[dt], 0, 0, 0);
            opv[dt] = __builtin_amdgcn_mfma_f32_16x16x32_bf16(pf1, vf1, opv[dt], 0, 0, 0);
        }
    }

    // epilogue: AO[b, l, h*64+d] = opv / l_i
    #pragma unroll
    for (int r = 0; r < 4; ++r) {
        float inv = 1.f / l_i[r];
        int l = q0 + (lane >> 4) * 4 + r;
        #pragma unroll
        for (int dt = 0; dt < 4; ++dt)
            O[(size_t)(b * LL + l) * HID + h * 64 + dt * 16 + l15] = opv[dt][r] * inv;
    }
}

// ---------------- Output projection GEMM (fp32) ----------------
__global__ __launch_bounds__(256) void out_gemm_kernel(
    const float* __restrict__ AO, const float* __restrict__ Wo,
    float* __restrict__ out)
{
    __shared__ float As[16][132];
    __shared__ float Bs[16][132];

    const int mt = blockIdx.x;
    const int nt = blockIdx.y;
    const int mbase = mt * 128;
    const int nbase = nt * 128;

    const int tid = threadIdx.x;
    const int lr = tid >> 1;
    const int lk = (tid & 1) * 8;
    const int ty = tid >> 4, tx = tid & 15;
    const int m0 = ty * 8, n0 = tx * 8;

    float acc[8][8];
    #pragma unroll
    for (int i = 0; i < 8; ++i)
        #pragma unroll
        for (int j = 0; j < 8; ++j) acc[i][j] = 0.f;

    for (int kc = 0; kc < 512; kc += 16) {
        const float4* ap = (const float4*)(AO + (size_t)(mbase + lr) * 512 + kc + lk);
        float4 a0 = ap[0], a1 = ap[1];
        const float4* bp = (const float4*)(Wo + (size_t)(nbase + lr) * 512 + kc + lk);
        float4 b0 = bp[0], b1 = bp[1];
        __syncthreads();
        As[lk + 0][lr] = a0.x; As[lk + 1][lr] = a0.y; As[lk + 2][lr] = a0.z; As[lk + 3][lr] = a0.w;
        As[lk + 4][lr] = a1.x; As[lk + 5][lr] = a1.y; As[lk + 6][lr] = a1.z; As[lk + 7][lr] = a1.w;
        Bs[lk + 0][lr] = b0.x; Bs[lk + 1][lr] = b0.y; Bs[lk + 2][lr] = b0.z; Bs[lk + 3][lr] = b0.w;
        Bs[lk + 4][lr] = b1.x; Bs[lk + 5][lr] = b1.y; Bs[lk + 6][lr] = b1.z; Bs[lk + 7][lr] = b1.w;
        __syncthreads();
        #pragma unroll
        for (int k = 0; k < 16; ++k) {
            float a[8], bb[8];
            *(float4*)&a[0]  = *(const float4*)&As[k][m0];
            *(float4*)&a[4]  = *(const float4*)&As[k][m0 + 4];
            *(float4*)&bb[0] = *(const float4*)&Bs[k][n0];
            *(float4*)&bb[4] = *(const float4*)&Bs[k][n0 + 4];
            #pragma unroll
            for (int i = 0; i < 8; ++i)
                #pragma unroll
                for (int j = 0; j < 8; ++j)
                    acc[i][j] = fmaf(a[i], bb[j], acc[i][j]);
        }
    }

    #pragma unroll
    for (int i = 0; i < 8; ++i) {
        int m = mbase + m0 + i;
        float* dp = out + (size_t)m * 512 + nbase + n0;
        *(float4*)dp       = make_float4(acc[i][0], acc[i][1], acc[i][2], acc[i][3]);
        *(float4*)(dp + 4) = make_float4(acc[i][4], acc[i][5], acc[i][6], acc[i][7]);
    }
}

extern "C" void kernel_launch(void* const* d_in, const int* in_sizes, int n_in,
                              void* d_out, int out_size, void* d_ws, size_t ws_size,
                              hipStream_t stream) {
    const float* x  = (const float*)d_in[0];
    const float* Wq = (const float*)d_in[1];
    const float* Wk = (const float*)d_in[2];
    const float* Wv = (const float*)d_in[3];
    const float* Wo = (const float*)d_in[4];
    float* out = (float*)d_out;

    float* ws = (float*)d_ws;
    const size_t tblN = (size_t)LL * 32;            // 32768
    const size_t qkvN = (size_t)BB * HH * LL * 64;  // 4194304
    float* cos_t = ws;
    float* sin_t = cos_t + tblN;
    unsigned short* Qb = (unsigned short*)(sin_t + tblN);
    unsigned short* Kb = Qb + qkvN;
    unsigned short* Vt = Kb + qkvN;
    float* AO = (float*)(Vt + qkvN);

    hipLaunchKernelGGL(rope_table_kernel, dim3((LL * 32 + 255) / 256), dim3(256), 0, stream,
                       cos_t, sin_t);
    hipLaunchKernelGGL(qkv_gemm_kernel, dim3(64, 12), dim3(256), 0, stream,
                       x, Wq, Wk, Wv, Qb, Kb, Vt);
    hipLaunchKernelGGL(rope_apply_kernel, dim3((2 * BB * HH * LL * 32) / 256), dim3(256), 0, stream,
                       Qb, Kb, cos_t, sin_t);
    hipLaunchKernelGGL(attn_kernel, dim3(16, 64), dim3(256), 0, stream,
                       Qb, Kb, Vt, AO);
    hipLaunchKernelGGL(out_gemm_kernel, dim3(64, 4), dim3(256), 0, stream,
                       AO, Wo, out);
}

// Round 3
// 183.478 us; speedup vs baseline: 2.8045x; 1.9988x over previous
//
#include <hip/hip_runtime.h>
#include <math.h>

// RoPE+SDPA attention. Round 2: bf16-MFMA everywhere (QKV proj, attn, out proj).
// B=8 L=1024 H=8 Dh=64 HID=512.
// ws: cos f32[32K] | sin f32[32K] | Qb bf16[4M] | Kb bf16[4M] | Vt bf16[4M, B,H,D,L]
//     | xb bf16[4M] | Wqb/Wkb/Wvb/Wob bf16[256K each] | AOb bf16[4M]

#define BB 8
#define LL 1024
#define HH 8
#define DH 64
#define HID 512

typedef __bf16 bf16x8 __attribute__((ext_vector_type(8)));
typedef float f32x4 __attribute__((ext_vector_type(4)));
typedef unsigned short u16x8 __attribute__((ext_vector_type(8)));
typedef unsigned short u16x4 __attribute__((ext_vector_type(4)));

__device__ inline unsigned short f2bf(float f) {
    union { float f; unsigned u; } v; v.f = f;
    unsigned r = v.u + 0x7fffu + ((v.u >> 16) & 1u);
    return (unsigned short)(r >> 16);
}
__device__ inline float bf2f(unsigned short s) {
    union { unsigned u; float f; } v; v.u = ((unsigned)s) << 16;
    return v.f;
}

#define GLOAD_LDS16(g, l) __builtin_amdgcn_global_load_lds( \
    (const __attribute__((address_space(1))) unsigned int*)(g), \
    (__attribute__((address_space(3))) unsigned int*)(l), 16, 0, 0)

// ---------------- RoPE table ----------------
__global__ void rope_table_kernel(float* __restrict__ cos_t, float* __restrict__ sin_t) {
    int idx = blockIdx.x * blockDim.x + threadIdx.x;
    if (idx >= LL * 32) return;
    int l = idx >> 5, j = idx & 31;
    float inv = exp2f(-(float)j * (13.287712379549449f / 32.0f));
    float th = (float)l * inv;
    cos_t[idx] = cosf(th);
    sin_t[idx] = sinf(th);
}

// ---------------- fp32 -> bf16 convert (x and the four W's) ----------------
__global__ __launch_bounds__(256) void convert_kernel(
    const float* __restrict__ x, const float* __restrict__ Wq,
    const float* __restrict__ Wk, const float* __restrict__ Wv,
    const float* __restrict__ Wo,
    unsigned short* __restrict__ xb, unsigned short* __restrict__ wqb,
    unsigned short* __restrict__ wkb, unsigned short* __restrict__ wvb,
    unsigned short* __restrict__ wob)
{
    int blk = blockIdx.x;
    const float* s; unsigned short* d; int off;
    if (blk < 2048) { s = x; d = xb; off = blk; }
    else {
        int t = (blk - 2048) >> 7;
        off = (blk - 2048) & 127;
        s = (t == 0) ? Wq : (t == 1) ? Wk : (t == 2) ? Wv : Wo;
        d = (t == 0) ? wqb : (t == 1) ? wkb : (t == 2) ? wvb : wob;
    }
    size_t base = ((size_t)off * 256 + threadIdx.x) * 8;
    float4 a = *(const float4*)(s + base);
    float4 b = *(const float4*)(s + base + 4);
    u16x8 pk;
    pk[0] = f2bf(a.x); pk[1] = f2bf(a.y); pk[2] = f2bf(a.z); pk[3] = f2bf(a.w);
    pk[4] = f2bf(b.x); pk[5] = f2bf(b.y); pk[6] = f2bf(b.z); pk[7] = f2bf(b.w);
    *(u16x8*)(d + base) = pk;
}

// ---------------- QKV projection GEMM, bf16 MFMA (m97 structure) ------------
// C[m,n] = sum_k xb[m,k] * W[n,k].  Tile 128x128, BK=32, 4 waves (2x2).
__global__ __launch_bounds__(256) void qkv_gemm_kernel(
    const unsigned short* __restrict__ xb, const unsigned short* __restrict__ Wqb,
    const unsigned short* __restrict__ Wkb, const unsigned short* __restrict__ Wvb,
    unsigned short* __restrict__ Qb, unsigned short* __restrict__ Kb,
    unsigned short* __restrict__ Vt)
{
    __shared__ unsigned short As[128 * 32];
    __shared__ unsigned short Bs[128 * 32];

    const int mt = blockIdx.x;          // 0..63
    const int nt = blockIdx.y;          // 0..11
    const int mbase = mt * 128;
    const int mat = nt >> 2;            // 0=Q,1=K,2=V
    const unsigned short* W = (mat == 0) ? Wqb : ((mat == 1) ? Wkb : Wvb);
    const int nW = (nt & 3) * 128;

    const int tid = threadIdx.x;
    const int w = tid >> 6, lane = tid & 63;
    const int wr = w >> 1, wc = w & 1;
    const int l15 = lane & 15, koff = (lane >> 4) * 8;

    // staging: wave w stages tile rows [w*32, w*32+32), 16 rows per call
    const int srow = (lane >> 2);          // 0..15 within the 16-row group
    const int scol = (lane & 3) * 8;       // bf16 col

    f32x4 acc[4][4];
    #pragma unroll
    for (int i = 0; i < 4; ++i)
        #pragma unroll
        for (int j = 0; j < 4; ++j) acc[i][j] = (f32x4){0.f, 0.f, 0.f, 0.f};

    for (int kc = 0; kc < 512; kc += 32) {
        __syncthreads();
        #pragma unroll
        for (int j = 0; j < 2; ++j) {
            int row = w * 32 + j * 16;
            GLOAD_LDS16(xb + (size_t)(mbase + row + srow) * 512 + kc + scol,
                        As + row * 32);
            GLOAD_LDS16(W + (size_t)(nW + row + srow) * 512 + kc + scol,
                        Bs + row * 32);
        }
        __syncthreads();

        bf16x8 af[4], bf[4];
        #pragma unroll
        for (int mi = 0; mi < 4; ++mi)
            af[mi] = *(const bf16x8*)&As[(wr * 64 + mi * 16 + l15) * 32 + koff];
        #pragma unroll
        for (int ni = 0; ni < 4; ++ni)
            bf[ni] = *(const bf16x8*)&Bs[(wc * 64 + ni * 16 + l15) * 32 + koff];
        #pragma unroll
        for (int mi = 0; mi < 4; ++mi)
            #pragma unroll
            for (int ni = 0; ni < 4; ++ni)
                acc[mi][ni] = __builtin_amdgcn_mfma_f32_16x16x32_bf16(
                    af[mi], bf[ni], acc[mi][ni], 0, 0, 0);
    }

    const int h = (nt & 3) * 2 + wc;       // head within this matrix
    if (mat < 2) {
        unsigned short* D = (mat == 0) ? Qb : Kb;
        #pragma unroll
        for (int mi = 0; mi < 4; ++mi) {
            int m = mbase + wr * 64 + mi * 16 + (lane >> 4) * 4;
            int b = m >> 10, l0 = m & 1023;
            #pragma unroll
            for (int r = 0; r < 4; ++r) {
                size_t rowbase = ((size_t)(b * HH + h) * LL + l0 + r) * 64;
                #pragma unroll
                for (int ni = 0; ni < 4; ++ni)
                    D[rowbase + ni * 16 + l15] = f2bf(acc[mi][ni][r]);
            }
        }
    } else {
        // V transposed: Vt[b][h][d][l]
        #pragma unroll
        for (int mi = 0; mi < 4; ++mi) {
            int m = mbase + wr * 64 + mi * 16 + (lane >> 4) * 4;
            int b = m >> 10, l0 = m & 1023;
            #pragma unroll
            for (int ni = 0; ni < 4; ++ni) {
                int d = ni * 16 + l15;
                u16x4 pk;
                #pragma unroll
                for (int r = 0; r < 4; ++r) pk[r] = f2bf(acc[mi][ni][r]);
                *(u16x4*)(Vt + ((size_t)(b * HH + h) * 64 + d) * LL + l0) = pk;
            }
        }
    }
}

// ---------------- RoPE apply (bf16, vectorized; Q gets *0.125 folded) -------
__global__ __launch_bounds__(256) void rope_apply_kernel(
    unsigned short* __restrict__ q, unsigned short* __restrict__ k,
    const float* __restrict__ cos_t, const float* __restrict__ sin_t)
{
    int idx = blockIdx.x * blockDim.x + threadIdx.x;   // [0, 2*B*H*L*4)
    const int total = BB * HH * LL * 4;
    unsigned short* T = q;
    float sc = 0.125f;
    if (idx >= total) { T = k; idx -= total; sc = 1.0f; }
    int g = idx & 3;
    int bhl = idx >> 2;
    int l = bhl & (LL - 1);
    int j0 = g * 8;
    size_t base = (size_t)bhl * 64 + j0;
    u16x8 v0 = *(u16x8*)(T + base);
    u16x8 v1 = *(u16x8*)(T + base + 32);
    float4 c0 = *(const float4*)(cos_t + l * 32 + j0);
    float4 c1 = *(const float4*)(cos_t + l * 32 + j0 + 4);
    float4 s0 = *(const float4*)(sin_t + l * 32 + j0);
    float4 s1 = *(const float4*)(sin_t + l * 32 + j0 + 4);
    float cs[8] = {c0.x, c0.y, c0.z, c0.w, c1.x, c1.y, c1.z, c1.w};
    float sn[8] = {s0.x, s0.y, s0.z, s0.w, s1.x, s1.y, s1.z, s1.w};
    u16x8 o0, o1;
    #pragma unroll
    for (int i = 0; i < 8; ++i) {
        float x0 = bf2f(v0[i]), x1 = bf2f(v1[i]);
        o0[i] = f2bf((x0 * cs[i] - x1 * sn[i]) * sc);
        o1[i] = f2bf((x1 * cs[i] + x0 * sn[i]) * sc);
    }
    *(u16x8*)(T + base)      = o0;
    *(u16x8*)(T + base + 32) = o1;
}

// ---------------- Flash attention, bf16 MFMA (unchanged from round 1, bf16 AO)
__global__ __launch_bounds__(256) void attn_kernel(
    const unsigned short* __restrict__ Q, const unsigned short* __restrict__ K,
    const unsigned short* __restrict__ Vt, unsigned short* __restrict__ O)
{
    __shared__ unsigned short Plds[4][16][72];

    const int qt = blockIdx.x;
    const int bh = blockIdx.y;
    const int b = bh >> 3, h = bh & 7;
    const int tid = threadIdx.x;
    const int w = tid >> 6;
    const int lane = tid & 63;
    const int l15 = lane & 15;
    const int koff = (lane >> 4) * 8;

    const unsigned short* Qp = Q + (size_t)bh * LL * 64;
    const unsigned short* Kp = K + (size_t)bh * LL * 64;
    const unsigned short* Vp = Vt + (size_t)bh * 64 * LL;

    const int q0 = qt * 64 + w * 16;

    bf16x8 qf0 = *(const bf16x8*)(Qp + (size_t)(q0 + l15) * 64 + koff);
    bf16x8 qf1 = *(const bf16x8*)(Qp + (size_t)(q0 + l15) * 64 + koff + 32);

    float m_i[4], l_i[4];
    f32x4 opv[4];
    #pragma unroll
    for (int r = 0; r < 4; ++r) { m_i[r] = -1e30f; l_i[r] = 0.f; }
    #pragma unroll
    for (int dt = 0; dt < 4; ++dt) opv[dt] = (f32x4){0.f, 0.f, 0.f, 0.f};

    for (int kt = 0; kt < 16; ++kt) {
        const int kbase = kt * 64;

        f32x4 s[4];
        #pragma unroll
        for (int nt = 0; nt < 4; ++nt) {
            const unsigned short* kp = Kp + (size_t)(kbase + nt * 16 + l15) * 64 + koff;
            bf16x8 kf0 = *(const bf16x8*)kp;
            bf16x8 kf1 = *(const bf16x8*)(kp + 32);
            f32x4 z = {0.f, 0.f, 0.f, 0.f};
            z = __builtin_amdgcn_mfma_f32_16x16x32_bf16(qf0, kf0, z, 0, 0, 0);
            z = __builtin_amdgcn_mfma_f32_16x16x32_bf16(qf1, kf1, z, 0, 0, 0);
            s[nt] = z;
        }

        float alpha[4];
        #pragma unroll
        for (int r = 0; r < 4; ++r) {
            float mx = fmaxf(fmaxf(s[0][r], s[1][r]), fmaxf(s[2][r], s[3][r]));
            mx = fmaxf(mx, __shfl_xor(mx, 1));
            mx = fmaxf(mx, __shfl_xor(mx, 2));
            mx = fmaxf(mx, __shfl_xor(mx, 4));
            mx = fmaxf(mx, __shfl_xor(mx, 8));
            float mnew = fmaxf(m_i[r], mx);
            float a = __expf(m_i[r] - mnew);
            m_i[r] = mnew;
            alpha[r] = a;
            float rsum = 0.f;
            #pragma unroll
            for (int nt = 0; nt < 4; ++nt) {
                float p = __expf(s[nt][r] - mnew);
                s[nt][r] = p;
                rsum += p;
            }
            rsum += __shfl_xor(rsum, 1);
            rsum += __shfl_xor(rsum, 2);
            rsum += __shfl_xor(rsum, 4);
            rsum += __shfl_xor(rsum, 8);
            l_i[r] = l_i[r] * a + rsum;
        }
        #pragma unroll
        for (int dt = 0; dt < 4; ++dt)
            #pragma unroll
            for (int r = 0; r < 4; ++r) opv[dt][r] *= alpha[r];

        #pragma unroll
        for (int nt = 0; nt < 4; ++nt)
            #pragma unroll
            for (int r = 0; r < 4; ++r)
                Plds[w][(lane >> 4) * 4 + r][nt * 16 + l15] = f2bf(s[nt][r]);

        bf16x8 pf0 = *(const bf16x8*)&Plds[w][l15][koff];
        bf16x8 pf1 = *(const bf16x8*)&Plds[w][l15][koff + 32];

        #pragma unroll
        for (int dt = 0; dt < 4; ++dt) {
            const unsigned short* vp = Vp + (size_t)(dt * 16 + l15) * LL + kbase + koff;
            bf16x8 vf0 = *(const bf16x8*)vp;
            bf16x8 vf1 = *(const bf16x8*)(vp + 32);
            opv[dt] = __builtin_amdgcn_mfma_f32_16x16x32_bf16(pf0, vf0, opv[dt], 0, 0, 0);
            opv[dt] = __builtin_amdgcn_mfma_f32_16x16x32_bf16(pf1, vf1, opv[dt], 0, 0, 0);
        }
    }

    #pragma unroll
    for (int r = 0; r < 4; ++r) {
        float inv = 1.f / l_i[r];
        int l = q0 + (lane >> 4) * 4 + r;
        #pragma unroll
        for (int dt = 0; dt < 4; ++dt)
            O[(size_t)(b * LL + l) * HID + h * 64 + dt * 16 + l15] =
                f2bf(opv[dt][r] * inv);
    }
}

// ---------------- Output projection GEMM, bf16 MFMA --------------------------
__global__ __launch_bounds__(256) void out_gemm_kernel(
    const unsigned short* __restrict__ AOb, const unsigned short* __restrict__ Wob,
    float* __restrict__ out)
{
    __shared__ unsigned short As[128 * 32];
    __shared__ unsigned short Bs[128 * 32];

    const int mt = blockIdx.x;          // 0..63
    const int nt = blockIdx.y;          // 0..3
    const int mbase = mt * 128;
    const int nbase = nt * 128;

    const int tid = threadIdx.x;
    const int w = tid >> 6, lane = tid & 63;
    const int wr = w >> 1, wc = w & 1;
    const int l15 = lane & 15, koff = (lane >> 4) * 8;
    const int srow = (lane >> 2);
    const int scol = (lane & 3) * 8;

    f32x4 acc[4][4];
    #pragma unroll
    for (int i = 0; i < 4; ++i)
        #pragma unroll
        for (int j = 0; j < 4; ++j) acc[i][j] = (f32x4){0.f, 0.f, 0.f, 0.f};

    for (int kc = 0; kc < 512; kc += 32) {
        __syncthreads();
        #pragma unroll
        for (int j = 0; j < 2; ++j) {
            int row = w * 32 + j * 16;
            GLOAD_LDS16(AOb + (size_t)(mbase + row + srow) * 512 + kc + scol,
                        As + row * 32);
            GLOAD_LDS16(Wob + (size_t)(nbase + row + srow) * 512 + kc + scol,
                        Bs + row * 32);
        }
        __syncthreads();

        bf16x8 af[4], bf[4];
        #pragma unroll
        for (int mi = 0; mi < 4; ++mi)
            af[mi] = *(const bf16x8*)&As[(wr * 64 + mi * 16 + l15) * 32 + koff];
        #pragma unroll
        for (int ni = 0; ni < 4; ++ni)
            bf[ni] = *(const bf16x8*)&Bs[(wc * 64 + ni * 16 + l15) * 32 + koff];
        #pragma unroll
        for (int mi = 0; mi < 4; ++mi)
            #pragma unroll
            for (int ni = 0; ni < 4; ++ni)
                acc[mi][ni] = __builtin_amdgcn_mfma_f32_16x16x32_bf16(
                    af[mi], bf[ni], acc[mi][ni], 0, 0, 0);
    }

    #pragma unroll
    for (int mi = 0; mi < 4; ++mi) {
        int m = mbase + wr * 64 + mi * 16 + (lane >> 4) * 4;
        #pragma unroll
        for (int r = 0; r < 4; ++r) {
            size_t rowbase = (size_t)(m + r) * 512 + nbase + wc * 64;
            #pragma unroll
            for (int ni = 0; ni < 4; ++ni)
                out[rowbase + ni * 16 + l15] = acc[mi][ni][r];
        }
    }
}

extern "C" void kernel_launch(void* const* d_in, const int* in_sizes, int n_in,
                              void* d_out, int out_size, void* d_ws, size_t ws_size,
                              hipStream_t stream) {
    const float* x  = (const float*)d_in[0];
    const float* Wq = (const float*)d_in[1];
    const float* Wk = (const float*)d_in[2];
    const float* Wv = (const float*)d_in[3];
    const float* Wo = (const float*)d_in[4];
    float* out = (float*)d_out;

    const size_t tblN = (size_t)LL * 32;            // 32768 floats
    const size_t qkvN = (size_t)BB * HH * LL * 64;  // 4194304 elems
    const size_t wN   = (size_t)HID * HID;          // 262144 elems

    float* cos_t = (float*)d_ws;
    float* sin_t = cos_t + tblN;
    unsigned short* Qb  = (unsigned short*)(sin_t + tblN);
    unsigned short* Kb  = Qb + qkvN;
    unsigned short* Vt  = Kb + qkvN;
    unsigned short* xb  = Vt + qkvN;
    unsigned short* Wqb = xb + qkvN;
    unsigned short* Wkb = Wqb + wN;
    unsigned short* Wvb = Wkb + wN;
    unsigned short* Wob = Wvb + wN;
    unsigned short* AOb = Wob + wN;

    hipLaunchKernelGGL(rope_table_kernel, dim3((LL * 32 + 255) / 256), dim3(256), 0, stream,
                       cos_t, sin_t);
    hipLaunchKernelGGL(convert_kernel, dim3(2048 + 512), dim3(256), 0, stream,
                       x, Wq, Wk, Wv, Wo, xb, Wqb, Wkb, Wvb, Wob);
    hipLaunchKernelGGL(qkv_gemm_kernel, dim3(64, 12), dim3(256), 0, stream,
                       xb, Wqb, Wkb, Wvb, Qb, Kb, Vt);
    hipLaunchKernelGGL(rope_apply_kernel, dim3((2 * BB * HH * LL * 4) / 256), dim3(256), 0, stream,
                       Qb, Kb, cos_t, sin_t);
    hipLaunchKernelGGL(attn_kernel, dim3(16, 64), dim3(256), 0, stream,
                       Qb, Kb, Vt, AOb);
    hipLaunchKernelGGL(out_gemm_kernel, dim3(64, 4), dim3(256), 0, stream,
                       AOb, Wob, out);
}